// Round 7
// baseline (1299.188 us; speedup 1.0000x reference)
//
#include <hip/hip_runtime.h>

#define F_IN 33
#define FP 36      // padded input cols for gcn gather (18 uints)
#define C 128      // F_OUT
#define GROWS 16   // rows per block in dense kernels
#define MAXDEG 128 // LDS-staged score/alpha cap per node

__device__ __forceinline__ unsigned short f2bf(float f) {
  unsigned u = __float_as_uint(f);
  unsigned r = (u + 0x7fff + ((u >> 16) & 1)) >> 16;   // RNE
  return (unsigned short)r;
}
__device__ __forceinline__ unsigned pack2(float lo, float hi) {
  return (unsigned)f2bf(lo) | ((unsigned)f2bf(hi) << 16);
}
__device__ __forceinline__ float bflo(unsigned u) { return __uint_as_float(u << 16); }
__device__ __forceinline__ float bfhi(unsigned u) { return __uint_as_float(u & 0xffff0000u); }

// ---- CSR build -------------------------------------------------------------

__global__ void count_kernel(const int* __restrict__ col, const float* __restrict__ w,
                             int* __restrict__ cnt, float* __restrict__ deg, int E) {
  int e = blockIdx.x * blockDim.x + threadIdx.x;
  if (e < E) {
    int c = col[e];
    atomicAdd(&cnt[c], 1);
    atomicAdd(&deg[c], w[e]);
  }
}

__global__ void scan1_kernel(const int* __restrict__ cnt, int* __restrict__ out,
                             int* __restrict__ bsum, int n) {
  __shared__ int lds[256];
  int t = threadIdx.x;
  int base = blockIdx.x * 1024 + t * 4;
  int v0 = (base + 0 < n) ? cnt[base + 0] : 0;
  int v1 = (base + 1 < n) ? cnt[base + 1] : 0;
  int v2 = (base + 2 < n) ? cnt[base + 2] : 0;
  int v3 = (base + 3 < n) ? cnt[base + 3] : 0;
  int tot = v0 + v1 + v2 + v3;
  lds[t] = tot;
  __syncthreads();
  for (int o = 1; o < 256; o <<= 1) {
    int x = (t >= o) ? lds[t - o] : 0;
    __syncthreads();
    lds[t] += x;
    __syncthreads();
  }
  int excl = lds[t] - tot;
  if (t == 255) bsum[blockIdx.x] = lds[255];
  if (base + 0 < n) out[base + 0] = excl;
  if (base + 1 < n) out[base + 1] = excl + v0;
  if (base + 2 < n) out[base + 2] = excl + v0 + v1;
  if (base + 3 < n) out[base + 3] = excl + v0 + v1 + v2;
}

__global__ void scan2_kernel(int* __restrict__ bsum, int nb) {
  __shared__ int lds[256];
  int t = threadIdx.x;
  int v = (t < nb) ? bsum[t] : 0;
  lds[t] = v;
  __syncthreads();
  for (int o = 1; o < 256; o <<= 1) {
    int x = (t >= o) ? lds[t - o] : 0;
    __syncthreads();
    lds[t] += x;
    __syncthreads();
  }
  if (t < nb) bsum[t] = lds[t] - v;
}

__global__ void scan3_dinv_kernel(int* __restrict__ off, const int* __restrict__ bsum,
                                  const float* __restrict__ deg, float* __restrict__ dinv,
                                  int n, int N) {
  int i = blockIdx.x * blockDim.x + threadIdx.x;
  if (i < n) off[i] += bsum[i >> 10];
  if (i < N) dinv[i] = rsqrtf(deg[i] + 1.0f);
}

__global__ void scatter_kernel(const int* __restrict__ row, const int* __restrict__ col,
                               const float* __restrict__ w, const int* __restrict__ off,
                               const float* __restrict__ dinv, int* __restrict__ cur,
                               int2* __restrict__ sedge, int E) {
  int e = blockIdx.x * blockDim.x + threadIdx.x;
  if (e < E) {
    int c = col[e];
    int r = row[e];
    int p = off[c] + atomicAdd(&cur[c], 1);
    sedge[p] = make_int2(r, __float_as_int(dinv[r] * w[e]));
  }
}

// ---- parameter prep --------------------------------------------------------

__global__ void prep_dots_kernel(const float* __restrict__ W1, const float* __restrict__ as1,
                                 const float* __restrict__ ad1, const float* __restrict__ W2,
                                 const float* __restrict__ as2, const float* __restrict__ ad2,
                                 float* __restrict__ attv) {
  int t = blockIdx.x * 256 + threadIdx.x;
  if (t >= 1024) return;
  int layer = t >> 9, rem = t & 511, sd = rem >> 8, rem2 = rem & 255;
  int h = rem2 >> 7, k = rem2 & 127;
  const float* W = layer ? W2 : W1;
  const float* att = sd ? (layer ? ad2 : ad1) : (layer ? as2 : as1);
  float s = 0.f;
  for (int c2 = 0; c2 < C; c2++) s += W[k * 2 * C + h * C + c2] * att[h * C + c2];
  attv[t] = s;
}

// Wp[(h*128+k)*128 + j] = W[k, h*128+j]
__global__ void prep_repack_kernel(const float* __restrict__ W1, const float* __restrict__ W2,
                                   float* __restrict__ Wp1, float* __restrict__ Wp2) {
  int t = blockIdx.x * 256 + threadIdx.x;   // 0..65535
  int layer = t >> 15, rem = t & 32767, hk = rem >> 7, j = rem & 127;
  int h = hk >> 7, k = hk & 127;
  const float* W = layer ? W2 : W1;
  float* Wp = layer ? Wp2 : Wp1;
  Wp[hk * C + j] = W[k * 2 * C + h * C + j];
}

__global__ void convert_x_kernel(const float* __restrict__ x, unsigned* __restrict__ X36U, int N) {
  int t = blockIdx.x * blockDim.x + threadIdx.x;
  if (t >= N * (FP / 2)) return;
  int n = t / (FP / 2);
  int p = t - n * (FP / 2);
  int c0 = 2 * p, c1 = 2 * p + 1;
  float f0 = (c0 < F_IN) ? x[n * F_IN + c0] : 0.f;
  float f1 = (c1 < F_IN) ? x[n * F_IN + c1] : 0.f;
  X36U[t] = pack2(f0, f1);
}

// ---- GCN (aggregate-then-project) -----------------------------------------

__global__ __launch_bounds__(256) void gcn_agg33_kernel(
    const unsigned* __restrict__ X36U, const int* __restrict__ off,
    const int2* __restrict__ sedge, const float* __restrict__ dinv,
    float* __restrict__ Xagg, int N) {
  int c = blockIdx.x * 4 + (threadIdx.x >> 6);
  if (c >= N) return;
  int l = threadIdx.x & 63;
  bool act = l < FP / 2;   // 18 active gather lanes
  float dc = dinv[c];
  unsigned uc = act ? X36U[(unsigned)c * (FP / 2) + l] : 0u;
  float A0x = dc * bflo(uc), A0y = dc * bfhi(uc);
  float A1x = 0.f, A1y = 0.f, A2x = 0.f, A2y = 0.f, A3x = 0.f, A3y = 0.f;
  int p = off[c], p1 = off[c + 1];
  for (; p + 4 <= p1; p += 4) {
    int2 e0 = sedge[p + 0], e1 = sedge[p + 1], e2 = sedge[p + 2], e3 = sedge[p + 3];
    unsigned u0 = 0, u1 = 0, u2 = 0, u3 = 0;
    if (act) {
      u0 = X36U[(unsigned)e0.x * (FP / 2) + l];
      u1 = X36U[(unsigned)e1.x * (FP / 2) + l];
      u2 = X36U[(unsigned)e2.x * (FP / 2) + l];
      u3 = X36U[(unsigned)e3.x * (FP / 2) + l];
    }
    float w0 = __int_as_float(e0.y), w1 = __int_as_float(e1.y);
    float w2 = __int_as_float(e2.y), w3 = __int_as_float(e3.y);
    A0x += w0 * bflo(u0); A0y += w0 * bfhi(u0);
    A1x += w1 * bflo(u1); A1y += w1 * bfhi(u1);
    A2x += w2 * bflo(u2); A2y += w2 * bfhi(u2);
    A3x += w3 * bflo(u3); A3y += w3 * bfhi(u3);
  }
  for (; p < p1; p++) {
    int2 e0 = sedge[p];
    unsigned u0 = act ? X36U[(unsigned)e0.x * (FP / 2) + l] : 0u;
    float w0 = __int_as_float(e0.y);
    A0x += w0 * bflo(u0); A0y += w0 * bfhi(u0);
  }
  if (act) {
    float2 o;
    o.x = dc * (A0x + A1x + A2x + A3x);
    o.y = dc * (A0y + A1y + A2y + A3y);
    ((float2*)Xagg)[(unsigned)c * (FP / 2) + l] = o;
  }
}

// H = relu(Xagg @ W33 + b); Hb bf16; score dots. x reads are wave-uniform
// (scalar path) -- no LDS in the GEMM loop.
__global__ __launch_bounds__(128) void gemm36_kernel(
    const float* __restrict__ Xagg, const float* __restrict__ W,
    const float* __restrict__ b, const float* __restrict__ wsv,
    const float* __restrict__ wdv, float* __restrict__ H,
    unsigned short* __restrict__ Hb, float* __restrict__ asrc,
    float* __restrict__ adst, int N) {
  int n0 = blockIdx.x * GROWS;
  int j = threadIdx.x;   // 0..127
  __shared__ float xls[GROWS * 132];  // 8.4 KB (dots staging only)
  float acc[GROWS];
  #pragma unroll
  for (int r = 0; r < GROWS; r++) acc[r] = 0.f;
  if (n0 + GROWS <= N) {
    for (int k4 = 0; k4 < 32; k4 += 4) {
      float w0 = W[(k4 + 0) * C + j], w1 = W[(k4 + 1) * C + j];
      float w2 = W[(k4 + 2) * C + j], w3 = W[(k4 + 3) * C + j];
      #pragma unroll
      for (int r = 0; r < GROWS; r++) {
        float4 a = *(const float4*)(Xagg + (size_t)(n0 + r) * FP + k4);  // uniform
        acc[r] += a.x * w0 + a.y * w1 + a.z * w2 + a.w * w3;
      }
    }
    float w32 = W[32 * C + j];
    #pragma unroll
    for (int r = 0; r < GROWS; r++) acc[r] += Xagg[(size_t)(n0 + r) * FP + 32] * w32;
  } else {
    int nr = N - n0;
    for (int k = 0; k < F_IN; k++) {
      float wv = W[k * C + j];
      for (int r = 0; r < nr; r++) acc[r] += Xagg[(size_t)(n0 + r) * FP + k] * wv;
    }
  }
  #pragma unroll
  for (int r = 0; r < GROWS; r++) {
    int n = n0 + r;
    float v = fmaxf(acc[r] + b[j], 0.f);
    if (n < N) {
      H[(size_t)n * C + j] = v;
      Hb[(size_t)n * C + j] = f2bf(v);
    }
    xls[r * 132 + j] = v;
  }
  __syncthreads();
  int r = j >> 3, sub = j & 7;
  float sa0 = 0.f, sd0 = 0.f, sa1 = 0.f, sd1 = 0.f;
  for (int k = sub; k < C; k += 8) {
    float v = xls[r * 132 + k];
    sa0 += v * wsv[k];      sd0 += v * wdv[k];
    sa1 += v * wsv[C + k];  sd1 += v * wdv[C + k];
  }
  #pragma unroll
  for (int o = 4; o > 0; o >>= 1) {
    sa0 += __shfl_down(sa0, o); sd0 += __shfl_down(sd0, o);
    sa1 += __shfl_down(sa1, o); sd1 += __shfl_down(sd1, o);
  }
  int n = n0 + r;
  if (sub == 0 && n < N) {
    asrc[n * 2 + 0] = sa0; adst[n * 2 + 0] = sd0;
    asrc[n * 2 + 1] = sa1; adst[n * 2 + 1] = sd1;
  }
}

// ---- GAT edge softmax + input-space aggregate ------------------------------
// Agg [N,256] f32: cols [0..127]=head0, [128..255]=head1 (K axis = (h,k))
__global__ __launch_bounds__(256) void gat_agg_kernel(
    const unsigned* __restrict__ HbU, const float* __restrict__ asrc,
    const float* __restrict__ adst, const int* __restrict__ off,
    const int2* __restrict__ sedge, float* __restrict__ Agg, int N) {
  __shared__ float2 lsc[4][MAXDEG];   // 4 KB
  int slot = threadIdx.x >> 6;
  int c = blockIdx.x * 4 + slot;
  if (c >= N) return;                 // wave-local LDS only, no barriers
  int l = threadIdx.x & 63;
  float2 adc = ((const float2*)adst)[c];
  float2 asc = ((const float2*)asrc)[c];
  int p0 = off[c], p1 = off[c + 1];
  int deg = p1 - p0;
  float e00 = asc.x + adc.x; e00 = e00 > 0.f ? e00 : 0.2f * e00;
  float e01 = asc.y + adc.y; e01 = e01 > 0.f ? e01 : 0.2f * e01;
  float m0 = e00, m1 = e01;
  for (int p = p0 + l; p < p1; p += 64) {
    int r = sedge[p].x;
    float2 av = ((const float2*)asrc)[r];
    float e0 = av.x + adc.x; e0 = e0 > 0.f ? e0 : 0.2f * e0;
    float e1 = av.y + adc.y; e1 = e1 > 0.f ? e1 : 0.2f * e1;
    int i = p - p0;
    if (i < MAXDEG) lsc[slot][i] = make_float2(e0, e1);
    m0 = fmaxf(m0, e0); m1 = fmaxf(m1, e1);
  }
  #pragma unroll
  for (int o = 32; o > 0; o >>= 1) {
    m0 = fmaxf(m0, __shfl_xor(m0, o));
    m1 = fmaxf(m1, __shfl_xor(m1, o));
  }
  int nl = deg < MAXDEG ? deg : MAXDEG;
  float s0 = 0.f, s1 = 0.f;
  for (int i = l; i < nl; i += 64) {
    float2 sc = lsc[slot][i];
    float a0 = __expf(sc.x - m0), a1 = __expf(sc.y - m1);
    lsc[slot][i] = make_float2(a0, a1);
    s0 += a0; s1 += a1;
  }
  for (int p = p0 + MAXDEG + l; p < p1; p += 64) {   // rare tail
    int r = sedge[p].x;
    float2 av = ((const float2*)asrc)[r];
    float e0 = av.x + adc.x; e0 = e0 > 0.f ? e0 : 0.2f * e0;
    float e1 = av.y + adc.y; e1 = e1 > 0.f ? e1 : 0.2f * e1;
    s0 += __expf(e0 - m0); s1 += __expf(e1 - m1);
  }
  #pragma unroll
  for (int o = 32; o > 0; o >>= 1) { s0 += __shfl_xor(s0, o); s1 += __shfl_xor(s1, o); }
  float w0 = __expf(e00 - m0), w1 = __expf(e01 - m1);
  s0 += w0; s1 += w1;
  float inv0 = 1.f / s0, inv1 = 1.f / s1;
  unsigned uc = HbU[(unsigned)c * 64 + l];
  float a00 = w0 * bflo(uc), a01 = w0 * bfhi(uc);
  float a10 = w1 * bflo(uc), a11 = w1 * bfhi(uc);
  float b00 = 0.f, b01 = 0.f, b10 = 0.f, b11 = 0.f;
  int i = 0;
  for (; i + 8 <= nl; i += 8) {
    int r0 = sedge[p0 + i + 0].x, r1 = sedge[p0 + i + 1].x;
    int r2 = sedge[p0 + i + 2].x, r3 = sedge[p0 + i + 3].x;
    int r4 = sedge[p0 + i + 4].x, r5 = sedge[p0 + i + 5].x;
    int r6 = sedge[p0 + i + 6].x, r7 = sedge[p0 + i + 7].x;
    unsigned u0 = HbU[(unsigned)r0 * 64 + l];
    unsigned u1 = HbU[(unsigned)r1 * 64 + l];
    unsigned u2 = HbU[(unsigned)r2 * 64 + l];
    unsigned u3 = HbU[(unsigned)r3 * 64 + l];
    unsigned u4 = HbU[(unsigned)r4 * 64 + l];
    unsigned u5 = HbU[(unsigned)r5 * 64 + l];
    unsigned u6 = HbU[(unsigned)r6 * 64 + l];
    unsigned u7 = HbU[(unsigned)r7 * 64 + l];
    float2 f0 = lsc[slot][i + 0], f1 = lsc[slot][i + 1];
    float2 f2 = lsc[slot][i + 2], f3 = lsc[slot][i + 3];
    float2 f4 = lsc[slot][i + 4], f5 = lsc[slot][i + 5];
    float2 f6 = lsc[slot][i + 6], f7 = lsc[slot][i + 7];
    a00 += f0.x * bflo(u0); a01 += f0.x * bfhi(u0); a10 += f0.y * bflo(u0); a11 += f0.y * bfhi(u0);
    b00 += f1.x * bflo(u1); b01 += f1.x * bfhi(u1); b10 += f1.y * bflo(u1); b11 += f1.y * bfhi(u1);
    a00 += f2.x * bflo(u2); a01 += f2.x * bfhi(u2); a10 += f2.y * bflo(u2); a11 += f2.y * bfhi(u2);
    b00 += f3.x * bflo(u3); b01 += f3.x * bfhi(u3); b10 += f3.y * bflo(u3); b11 += f3.y * bfhi(u3);
    a00 += f4.x * bflo(u4); a01 += f4.x * bfhi(u4); a10 += f4.y * bflo(u4); a11 += f4.y * bfhi(u4);
    b00 += f5.x * bflo(u5); b01 += f5.x * bfhi(u5); b10 += f5.y * bflo(u5); b11 += f5.y * bfhi(u5);
    a00 += f6.x * bflo(u6); a01 += f6.x * bfhi(u6); a10 += f6.y * bflo(u6); a11 += f6.y * bfhi(u6);
    b00 += f7.x * bflo(u7); b01 += f7.x * bfhi(u7); b10 += f7.y * bflo(u7); b11 += f7.y * bfhi(u7);
  }
  for (; i < nl; i++) {
    int r0 = sedge[p0 + i].x;
    unsigned u0 = HbU[(unsigned)r0 * 64 + l];
    float2 f0 = lsc[slot][i];
    a00 += f0.x * bflo(u0); a01 += f0.x * bfhi(u0);
    a10 += f0.y * bflo(u0); a11 += f0.y * bfhi(u0);
  }
  for (int p = p0 + MAXDEG; p < p1; p++) {   // rare tail: recompute alpha
    int r = sedge[p].x;
    float2 av = ((const float2*)asrc)[r];
    float e0 = av.x + adc.x; e0 = e0 > 0.f ? e0 : 0.2f * e0;
    float e1 = av.y + adc.y; e1 = e1 > 0.f ? e1 : 0.2f * e1;
    float al0 = __expf(e0 - m0), al1 = __expf(e1 - m1);
    unsigned u0 = HbU[(unsigned)r * 64 + l];
    a00 += al0 * bflo(u0); a01 += al0 * bfhi(u0);
    a10 += al1 * bflo(u0); a11 += al1 * bfhi(u0);
  }
  ((float2*)Agg)[(size_t)c * 128 + l]      = make_float2((a00 + b00) * inv0, (a01 + b01) * inv0);
  ((float2*)Agg)[(size_t)c * 128 + 64 + l] = make_float2((a10 + b10) * inv1, (a11 + b11) * inv1);
}

// out = 0.5*(Agg @ Wp) + b (+relu); K=256; Agg reads wave-uniform (scalar path)
__global__ __launch_bounds__(128) void post_gemm_kernel(
    const float* __restrict__ Agg, const float* __restrict__ Wp,
    const float* __restrict__ b, float* __restrict__ out, int relu, int N) {
  int n0 = blockIdx.x * GROWS;
  int j = threadIdx.x;   // 0..127
  float acc[GROWS];
  #pragma unroll
  for (int r = 0; r < GROWS; r++) acc[r] = 0.f;
  if (n0 + GROWS <= N) {
    for (int k4 = 0; k4 < 256; k4 += 4) {
      float w0 = Wp[(k4 + 0) * C + j], w1 = Wp[(k4 + 1) * C + j];
      float w2 = Wp[(k4 + 2) * C + j], w3 = Wp[(k4 + 3) * C + j];
      #pragma unroll
      for (int r = 0; r < GROWS; r++) {
        float4 a = *(const float4*)(Agg + (size_t)(n0 + r) * 256 + k4);  // uniform
        acc[r] += a.x * w0 + a.y * w1 + a.z * w2 + a.w * w3;
      }
    }
  } else {
    int nr = N - n0;
    for (int k = 0; k < 256; k++) {
      float wv = Wp[k * C + j];
      for (int r = 0; r < nr; r++) acc[r] += Agg[(size_t)(n0 + r) * 256 + k] * wv;
    }
  }
  #pragma unroll
  for (int r = 0; r < GROWS; r++) {
    int n = n0 + r;
    if (n < N) {
      float v = 0.5f * acc[r] + b[j];
      if (relu) v = fmaxf(v, 0.f);
      out[(size_t)n * C + j] = v;
    }
  }
}

// ---- gated blend: z-GEMMs with wave-uniform x reads (no GEMM LDS) ----------
__global__ __launch_bounds__(128) void blend_kernel(
    const float* __restrict__ xt, const float* __restrict__ x,
    const float* __restrict__ fc1W, const float* __restrict__ fc1b,
    const float* __restrict__ fc2W, const float* __restrict__ fc2b,
    const float* __restrict__ pb, float* __restrict__ out,
    unsigned short* __restrict__ Hb2, const float* __restrict__ wsv,
    const float* __restrict__ wdv, float* __restrict__ asrc,
    float* __restrict__ adst, int dots, int N) {
  int n0 = blockIdx.x * GROWS;
  int j = threadIdx.x;   // 0..127
  __shared__ float xls[GROWS * 132];  // 8.4 KB (dots staging only)
  float s1[GROWS], s2[GROWS];
  #pragma unroll
  for (int r = 0; r < GROWS; r++) { s1[r] = 0.f; s2[r] = 0.f; }
  if (n0 + GROWS <= N) {
    for (int k4 = 0; k4 < C; k4 += 4) {
      float w1a = fc1W[(k4 + 0) * C + j], w2a = fc2W[(k4 + 0) * C + j];
      float w1b = fc1W[(k4 + 1) * C + j], w2b = fc2W[(k4 + 1) * C + j];
      float w1c = fc1W[(k4 + 2) * C + j], w2c = fc2W[(k4 + 2) * C + j];
      float w1d = fc1W[(k4 + 3) * C + j], w2d = fc2W[(k4 + 3) * C + j];
      #pragma unroll
      for (int r = 0; r < GROWS; r++) {
        float4 t4 = *(const float4*)(xt + (size_t)(n0 + r) * C + k4);  // uniform
        float4 x4 = *(const float4*)(x + (size_t)(n0 + r) * C + k4);   // uniform
        s1[r] += t4.x * w1a + t4.y * w1b + t4.z * w1c + t4.w * w1d;
        s2[r] += x4.x * w2a + x4.y * w2b + x4.z * w2c + x4.w * w2d;
      }
    }
  } else {
    int nr = N - n0;
    for (int k = 0; k < C; k++) {
      float w1 = fc1W[k * C + j], w2 = fc2W[k * C + j];
      for (int r = 0; r < nr; r++) {
        s1[r] += xt[(size_t)(n0 + r) * C + k] * w1;
        s2[r] += x[(size_t)(n0 + r) * C + k] * w2;
      }
    }
  }
  float bb = fc1b[j] + fc2b[j] + pb[j];
  #pragma unroll
  for (int r = 0; r < GROWS; r++) {
    int n = n0 + r;
    if (n < N) {
      float xtv = xt[(size_t)n * C + j];
      float xv  = x[(size_t)n * C + j];
      float t = s1[r] + s2[r] + bb;
      float z = 1.f / (1.f + __expf(-t));
      float o = z * xtv + (1.f - z) * xv;
      out[(size_t)n * C + j] = o;
      if (dots) Hb2[(size_t)n * C + j] = f2bf(o);
      xls[r * 132 + j] = o;
    } else {
      xls[r * 132 + j] = 0.f;
    }
  }
  if (!dots) return;
  __syncthreads();
  int r = j >> 3, sub = j & 7;
  float sa0 = 0.f, sd0 = 0.f, sa1 = 0.f, sd1 = 0.f;
  for (int k = sub; k < C; k += 8) {
    float v = xls[r * 132 + k];
    sa0 += v * wsv[k];      sd0 += v * wdv[k];
    sa1 += v * wsv[C + k];  sd1 += v * wdv[C + k];
  }
  #pragma unroll
  for (int o = 4; o > 0; o >>= 1) {
    sa0 += __shfl_down(sa0, o); sd0 += __shfl_down(sd0, o);
    sa1 += __shfl_down(sa1, o); sd1 += __shfl_down(sd1, o);
  }
  int n = n0 + r;
  if (sub == 0 && n < N) {
    asrc[n * 2 + 0] = sa0; adst[n * 2 + 0] = sd0;
    asrc[n * 2 + 1] = sa1; adst[n * 2 + 1] = sd1;
  }
}

// ---- launch ----------------------------------------------------------------

extern "C" void kernel_launch(void* const* d_in, const int* in_sizes, int n_in,
                              void* d_out, int out_size, void* d_ws, size_t ws_size,
                              hipStream_t stream) {
  const float* x_in  = (const float*)d_in[0];
  const int*   ei    = (const int*)d_in[1];
  const float* ew    = (const float*)d_in[2];
  const float* gcn_W = (const float*)d_in[3];
  const float* gcn_b = (const float*)d_in[4];
  const float* g1_W  = (const float*)d_in[5];
  const float* g1_as = (const float*)d_in[6];
  const float* g1_ad = (const float*)d_in[7];
  const float* g1_b  = (const float*)d_in[8];
  const float* g2_W  = (const float*)d_in[9];
  const float* g2_as = (const float*)d_in[10];
  const float* g2_ad = (const float*)d_in[11];
  const float* g2_b  = (const float*)d_in[12];
  const float* fc1_W = (const float*)d_in[13];
  const float* fc1_b = (const float*)d_in[14];
  const float* fc2_W = (const float*)d_in[15];
  const float* fc2_b = (const float*)d_in[16];
  const float* pb    = (const float*)d_in[17];

  const int N = in_sizes[0] / F_IN;
  const int E = in_sizes[2];
  const int* row = ei;
  const int* col = ei + E;

  char* ws = (char*)d_ws;
  size_t o = 0;
  auto alloc = [&](size_t bytes) -> void* {
    void* p = ws + o;
    o += (bytes + 255) & ~(size_t)255;
    return p;
  };
  int*   cnt   = (int*)alloc((size_t)(N + 1) * 4);
  int*   cur   = (int*)alloc((size_t)N * 4);
  float* deg   = (float*)alloc((size_t)N * 4);
  size_t zero_bytes = o;                     // cnt+cur+deg at ws start
  int*   off   = (int*)alloc((size_t)(N + 1) * 4);
  float* dinv  = (float*)alloc((size_t)N * 4);
  int*   bsum  = (int*)alloc(256 * 4);
  int2*  sedge = (int2*)alloc((size_t)E * 8);
  float* attv  = (float*)alloc(1024 * 4);                 // ws1,wd1,ws2,wd2
  float* Wp1   = (float*)alloc((size_t)256 * C * 4);
  float* Wp2   = (float*)alloc((size_t)256 * C * 4);
  float* asrc  = (float*)alloc((size_t)N * 2 * 4);
  float* adst  = (float*)alloc((size_t)N * 2 * 4);
  unsigned* X36U = (unsigned*)alloc((size_t)N * (FP / 2) * 4);   // bf16 [N,36]
  float* Xagg  = (float*)alloc((size_t)N * FP * 4);
  float* H     = (float*)alloc((size_t)N * C * 4);        // gcn out
  unsigned short* Hb  = (unsigned short*)alloc((size_t)N * C * 2);
  float* Agg   = (float*)alloc((size_t)N * 256 * 4);      // f32 [N,2,128]
  float* XT    = (float*)alloc((size_t)N * C * 4);        // gat out
  float* H2    = (float*)alloc((size_t)N * C * 4);        // blend1 out
  unsigned short* Hb2 = (unsigned short*)alloc((size_t)N * C * 2);
  (void)ws_size; (void)n_in; (void)out_size;

  float* ws1 = attv + 0,   *wd1 = attv + 256;
  float* ws2 = attv + 512, *wd2 = attv + 768;

  hipMemsetAsync(d_ws, 0, zero_bytes, stream);

  const int tb = 256;
  const int nP = N + 1;
  const int nb = (nP + 1023) / 1024;

  // parameter prep (input-only deps)
  prep_dots_kernel<<<4, 256, 0, stream>>>(g1_W, g1_as, g1_ad, g2_W, g2_as, g2_ad, attv);
  prep_repack_kernel<<<256, 256, 0, stream>>>(g1_W, g2_W, Wp1, Wp2);
  convert_x_kernel<<<(N * (FP / 2) + tb - 1) / tb, tb, 0, stream>>>(x_in, X36U, N);

  // CSR build
  count_kernel<<<(E + tb - 1) / tb, tb, 0, stream>>>(col, ew, cnt, deg, E);
  scan1_kernel<<<nb, 256, 0, stream>>>(cnt, off, bsum, nP);
  scan2_kernel<<<1, 256, 0, stream>>>(bsum, nb);
  scan3_dinv_kernel<<<(nP + tb - 1) / tb, tb, 0, stream>>>(off, bsum, deg, dinv, nP, N);
  scatter_kernel<<<(E + tb - 1) / tb, tb, 0, stream>>>(row, col, ew, off, dinv, cur, sedge, E);

  // GCN: aggregate 33-dim inputs, then project (+relu, +layer1 score dots)
  gcn_agg33_kernel<<<(N + 3) / 4, 256, 0, stream>>>(X36U, off, sedge, dinv, Xagg, N);
  gemm36_kernel<<<(N + GROWS - 1) / GROWS, C, 0, stream>>>(Xagg, gcn_W, gcn_b, ws1, wd1,
                                                           H, Hb, asrc, adst, N);

  // GAT layer 1: softmax+aggregate in input space, project, blend (+layer2 dots)
  gat_agg_kernel<<<(N + 3) / 4, 256, 0, stream>>>((const unsigned*)Hb, asrc, adst, off, sedge, Agg, N);
  post_gemm_kernel<<<(N + GROWS - 1) / GROWS, C, 0, stream>>>(Agg, Wp1, g1_b, XT, 1, N);
  blend_kernel<<<(N + GROWS - 1) / GROWS, C, 0, stream>>>(XT, H, fc1_W, fc1_b, fc2_W, fc2_b, pb,
                                                          H2, Hb2, ws2, wd2, asrc, adst, 1, N);

  // GAT layer 2 + final blend into d_out
  gat_agg_kernel<<<(N + 3) / 4, 256, 0, stream>>>((const unsigned*)Hb2, asrc, adst, off, sedge, Agg, N);
  post_gemm_kernel<<<(N + GROWS - 1) / GROWS, C, 0, stream>>>(Agg, Wp2, g2_b, XT, 0, N);
  blend_kernel<<<(N + GROWS - 1) / GROWS, C, 0, stream>>>(XT, H2, fc1_W, fc1_b, fc2_W, fc2_b, pb,
                                                          (float*)d_out, (unsigned short*)0,
                                                          ws2, wd2, asrc, adst, 0, N);
}

// Round 8
// 1008.563 us; speedup vs baseline: 1.2882x; 1.2882x over previous
//
#include <hip/hip_runtime.h>

#define F_IN 33
#define FP 36      // padded input cols for gcn gather (18 uints)
#define C 128      // F_OUT
#define GROWS 16   // rows per block in dense kernels
#define MAXDEG 128 // LDS-staged score/alpha cap per node

__device__ __forceinline__ unsigned short f2bf(float f) {
  unsigned u = __float_as_uint(f);
  unsigned r = (u + 0x7fff + ((u >> 16) & 1)) >> 16;   // RNE
  return (unsigned short)r;
}
__device__ __forceinline__ unsigned pack2(float lo, float hi) {
  return (unsigned)f2bf(lo) | ((unsigned)f2bf(hi) << 16);
}
__device__ __forceinline__ float bflo(unsigned u) { return __uint_as_float(u << 16); }
__device__ __forceinline__ float bfhi(unsigned u) { return __uint_as_float(u & 0xffff0000u); }

// ---- CSR build -------------------------------------------------------------

__global__ void count_kernel(const int* __restrict__ col, const float* __restrict__ w,
                             int* __restrict__ cnt, float* __restrict__ deg, int E) {
  int e = blockIdx.x * blockDim.x + threadIdx.x;
  if (e < E) {
    int c = col[e];
    atomicAdd(&cnt[c], 1);
    atomicAdd(&deg[c], w[e]);
  }
}

__global__ void scan1_kernel(const int* __restrict__ cnt, int* __restrict__ out,
                             int* __restrict__ bsum, int n) {
  __shared__ int lds[256];
  int t = threadIdx.x;
  int base = blockIdx.x * 1024 + t * 4;
  int v0 = (base + 0 < n) ? cnt[base + 0] : 0;
  int v1 = (base + 1 < n) ? cnt[base + 1] : 0;
  int v2 = (base + 2 < n) ? cnt[base + 2] : 0;
  int v3 = (base + 3 < n) ? cnt[base + 3] : 0;
  int tot = v0 + v1 + v2 + v3;
  lds[t] = tot;
  __syncthreads();
  for (int o = 1; o < 256; o <<= 1) {
    int x = (t >= o) ? lds[t - o] : 0;
    __syncthreads();
    lds[t] += x;
    __syncthreads();
  }
  int excl = lds[t] - tot;
  if (t == 255) bsum[blockIdx.x] = lds[255];
  if (base + 0 < n) out[base + 0] = excl;
  if (base + 1 < n) out[base + 1] = excl + v0;
  if (base + 2 < n) out[base + 2] = excl + v0 + v1;
  if (base + 3 < n) out[base + 3] = excl + v0 + v1 + v2;
}

__global__ void scan2_kernel(int* __restrict__ bsum, int nb) {
  __shared__ int lds[256];
  int t = threadIdx.x;
  int v = (t < nb) ? bsum[t] : 0;
  lds[t] = v;
  __syncthreads();
  for (int o = 1; o < 256; o <<= 1) {
    int x = (t >= o) ? lds[t - o] : 0;
    __syncthreads();
    lds[t] += x;
    __syncthreads();
  }
  if (t < nb) bsum[t] = lds[t] - v;
}

__global__ void scan3_dinv_kernel(int* __restrict__ off, const int* __restrict__ bsum,
                                  const float* __restrict__ deg, float* __restrict__ dinv,
                                  int n, int N) {
  int i = blockIdx.x * blockDim.x + threadIdx.x;
  if (i < n) off[i] += bsum[i >> 10];
  if (i < N) dinv[i] = rsqrtf(deg[i] + 1.0f);
}

__global__ void scatter_kernel(const int* __restrict__ row, const int* __restrict__ col,
                               const float* __restrict__ w, const int* __restrict__ off,
                               const float* __restrict__ dinv, int* __restrict__ cur,
                               int2* __restrict__ sedge, int E) {
  int e = blockIdx.x * blockDim.x + threadIdx.x;
  if (e < E) {
    int c = col[e];
    int r = row[e];
    int p = off[c] + atomicAdd(&cur[c], 1);
    sedge[p] = make_int2(r, __float_as_int(dinv[r] * w[e]));
  }
}

// ---- parameter prep --------------------------------------------------------

__global__ void prep_dots_kernel(const float* __restrict__ W1, const float* __restrict__ as1,
                                 const float* __restrict__ ad1, const float* __restrict__ W2,
                                 const float* __restrict__ as2, const float* __restrict__ ad2,
                                 float* __restrict__ attv) {
  int t = blockIdx.x * 256 + threadIdx.x;
  if (t >= 1024) return;
  int layer = t >> 9, rem = t & 511, sd = rem >> 8, rem2 = rem & 255;
  int h = rem2 >> 7, k = rem2 & 127;
  const float* W = layer ? W2 : W1;
  const float* att = sd ? (layer ? ad2 : ad1) : (layer ? as2 : as1);
  float s = 0.f;
  for (int c2 = 0; c2 < C; c2++) s += W[k * 2 * C + h * C + c2] * att[h * C + c2];
  attv[t] = s;
}

// Wp[(h*128+k)*128 + j] = W[k, h*128+j]
__global__ void prep_repack_kernel(const float* __restrict__ W1, const float* __restrict__ W2,
                                   float* __restrict__ Wp1, float* __restrict__ Wp2) {
  int t = blockIdx.x * 256 + threadIdx.x;   // 0..65535
  int layer = t >> 15, rem = t & 32767, hk = rem >> 7, j = rem & 127;
  int h = hk >> 7, k = hk & 127;
  const float* W = layer ? W2 : W1;
  float* Wp = layer ? Wp2 : Wp1;
  Wp[hk * C + j] = W[k * 2 * C + h * C + j];
}

// Wz = [fc1W ; fc2W]  (K=256 concat)
__global__ void prep_wz_kernel(const float* __restrict__ fc1W, const float* __restrict__ fc2W,
                               float* __restrict__ Wz) {
  int t = blockIdx.x * 256 + threadIdx.x;   // 0..32767
  if (t >= 32768) return;
  Wz[t] = (t < 16384) ? fc1W[t] : fc2W[t - 16384];
}

__global__ void convert_x_kernel(const float* __restrict__ x, unsigned* __restrict__ X36U, int N) {
  int t = blockIdx.x * blockDim.x + threadIdx.x;
  if (t >= N * (FP / 2)) return;
  int n = t / (FP / 2);
  int p = t - n * (FP / 2);
  int c0 = 2 * p, c1 = 2 * p + 1;
  float f0 = (c0 < F_IN) ? x[n * F_IN + c0] : 0.f;
  float f1 = (c1 < F_IN) ? x[n * F_IN + c1] : 0.f;
  X36U[t] = pack2(f0, f1);
}

// ---- GCN (aggregate-then-project) -----------------------------------------

__global__ __launch_bounds__(256) void gcn_agg33_kernel(
    const unsigned* __restrict__ X36U, const int* __restrict__ off,
    const int2* __restrict__ sedge, const float* __restrict__ dinv,
    float* __restrict__ Xagg, int N) {
  int c = blockIdx.x * 4 + (threadIdx.x >> 6);
  if (c >= N) return;
  int l = threadIdx.x & 63;
  bool act = l < FP / 2;   // 18 active gather lanes
  float dc = dinv[c];
  unsigned uc = act ? X36U[(unsigned)c * (FP / 2) + l] : 0u;
  float A0x = dc * bflo(uc), A0y = dc * bfhi(uc);
  float A1x = 0.f, A1y = 0.f, A2x = 0.f, A2y = 0.f, A3x = 0.f, A3y = 0.f;
  int p = off[c], p1 = off[c + 1];
  for (; p + 4 <= p1; p += 4) {
    int2 e0 = sedge[p + 0], e1 = sedge[p + 1], e2 = sedge[p + 2], e3 = sedge[p + 3];
    unsigned u0 = 0, u1 = 0, u2 = 0, u3 = 0;
    if (act) {
      u0 = X36U[(unsigned)e0.x * (FP / 2) + l];
      u1 = X36U[(unsigned)e1.x * (FP / 2) + l];
      u2 = X36U[(unsigned)e2.x * (FP / 2) + l];
      u3 = X36U[(unsigned)e3.x * (FP / 2) + l];
    }
    float w0 = __int_as_float(e0.y), w1 = __int_as_float(e1.y);
    float w2 = __int_as_float(e2.y), w3 = __int_as_float(e3.y);
    A0x += w0 * bflo(u0); A0y += w0 * bfhi(u0);
    A1x += w1 * bflo(u1); A1y += w1 * bfhi(u1);
    A2x += w2 * bflo(u2); A2y += w2 * bfhi(u2);
    A3x += w3 * bflo(u3); A3y += w3 * bfhi(u3);
  }
  for (; p < p1; p++) {
    int2 e0 = sedge[p];
    unsigned u0 = act ? X36U[(unsigned)e0.x * (FP / 2) + l] : 0u;
    float w0 = __int_as_float(e0.y);
    A0x += w0 * bflo(u0); A0y += w0 * bfhi(u0);
  }
  if (act) {
    float2 o;
    o.x = dc * (A0x + A1x + A2x + A3x);
    o.y = dc * (A0y + A1y + A2y + A3y);
    ((float2*)Xagg)[(unsigned)c * (FP / 2) + l] = o;
  }
}

// H = relu(Xagg @ W33 + b); Hb bf16; layer-1 score dots (round-6 LDS version)
__global__ void gemm36_kernel(const float* __restrict__ Xagg, const float* __restrict__ W,
                              const float* __restrict__ b, const float* __restrict__ wsv,
                              const float* __restrict__ wdv, float* __restrict__ H,
                              unsigned short* __restrict__ Hb, float* __restrict__ asrc,
                              float* __restrict__ adst, int N) {
  int n0 = blockIdx.x * GROWS;
  int j = threadIdx.x;   // 0..127
  __shared__ float xr[GROWS * FP];    // 2.3 KB
  __shared__ float xls[GROWS * 132];  // 8.4 KB
  {
    const float4* src = (const float4*)(Xagg + (size_t)n0 * FP);
    float4* dst = (float4*)xr;
    for (int i = j; i < GROWS * FP / 4; i += 128) dst[i] = src[i];  // N%16==0
  }
  __syncthreads();
  float acc[GROWS];
  #pragma unroll
  for (int r = 0; r < GROWS; r++) acc[r] = 0.f;
  #pragma unroll 3
  for (int k = 0; k < F_IN; k++) {
    float wv = W[k * C + j];
    #pragma unroll
    for (int r = 0; r < GROWS; r++) acc[r] += xr[r * FP + k] * wv;
  }
  #pragma unroll
  for (int r = 0; r < GROWS; r++) {
    int n = n0 + r;
    float v = fmaxf(acc[r] + b[j], 0.f);
    if (n < N) {
      H[(size_t)n * C + j] = v;
      Hb[(size_t)n * C + j] = f2bf(v);
    }
    xls[r * 132 + j] = v;
  }
  __syncthreads();
  int r = j >> 3, sub = j & 7;
  float sa0 = 0.f, sd0 = 0.f, sa1 = 0.f, sd1 = 0.f;
  for (int k = sub; k < C; k += 8) {
    float v = xls[r * 132 + k];
    sa0 += v * wsv[k];      sd0 += v * wdv[k];
    sa1 += v * wsv[C + k];  sd1 += v * wdv[C + k];
  }
  #pragma unroll
  for (int o = 4; o > 0; o >>= 1) {
    sa0 += __shfl_down(sa0, o); sd0 += __shfl_down(sd0, o);
    sa1 += __shfl_down(sa1, o); sd1 += __shfl_down(sd1, o);
  }
  int n = n0 + r;
  if (sub == 0 && n < N) {
    asrc[n * 2 + 0] = sa0; adst[n * 2 + 0] = sd0;
    asrc[n * 2 + 1] = sa1; adst[n * 2 + 1] = sd1;
  }
}

// ---- GAT edge softmax + input-space aggregate -> packed bf16 Agg ----------
__global__ __launch_bounds__(256) void gat_agg_kernel(
    const unsigned* __restrict__ HbU, const float* __restrict__ asrc,
    const float* __restrict__ adst, const int* __restrict__ off,
    const int2* __restrict__ sedge, unsigned* __restrict__ AggU, int N) {
  __shared__ float2 lsc[4][MAXDEG];   // 4 KB
  int slot = threadIdx.x >> 6;
  int c = blockIdx.x * 4 + slot;
  if (c >= N) return;                 // wave-local LDS only, no barriers
  int l = threadIdx.x & 63;
  float2 adc = ((const float2*)adst)[c];
  float2 asc = ((const float2*)asrc)[c];
  int p0 = off[c], p1 = off[c + 1];
  int deg = p1 - p0;
  float e00 = asc.x + adc.x; e00 = e00 > 0.f ? e00 : 0.2f * e00;
  float e01 = asc.y + adc.y; e01 = e01 > 0.f ? e01 : 0.2f * e01;
  float m0 = e00, m1 = e01;
  for (int p = p0 + l; p < p1; p += 64) {
    int r = sedge[p].x;
    float2 av = ((const float2*)asrc)[r];
    float e0 = av.x + adc.x; e0 = e0 > 0.f ? e0 : 0.2f * e0;
    float e1 = av.y + adc.y; e1 = e1 > 0.f ? e1 : 0.2f * e1;
    int i = p - p0;
    if (i < MAXDEG) lsc[slot][i] = make_float2(e0, e1);
    m0 = fmaxf(m0, e0); m1 = fmaxf(m1, e1);
  }
  #pragma unroll
  for (int o = 32; o > 0; o >>= 1) {
    m0 = fmaxf(m0, __shfl_xor(m0, o));
    m1 = fmaxf(m1, __shfl_xor(m1, o));
  }
  int nl = deg < MAXDEG ? deg : MAXDEG;
  float s0 = 0.f, s1 = 0.f;
  for (int i = l; i < nl; i += 64) {
    float2 sc = lsc[slot][i];
    float a0 = __expf(sc.x - m0), a1 = __expf(sc.y - m1);
    lsc[slot][i] = make_float2(a0, a1);
    s0 += a0; s1 += a1;
  }
  for (int p = p0 + MAXDEG + l; p < p1; p += 64) {   // rare tail
    int r = sedge[p].x;
    float2 av = ((const float2*)asrc)[r];
    float e0 = av.x + adc.x; e0 = e0 > 0.f ? e0 : 0.2f * e0;
    float e1 = av.y + adc.y; e1 = e1 > 0.f ? e1 : 0.2f * e1;
    s0 += __expf(e0 - m0); s1 += __expf(e1 - m1);
  }
  #pragma unroll
  for (int o = 32; o > 0; o >>= 1) { s0 += __shfl_xor(s0, o); s1 += __shfl_xor(s1, o); }
  float w0 = __expf(e00 - m0), w1 = __expf(e01 - m1);
  s0 += w0; s1 += w1;
  float inv0 = 1.f / s0, inv1 = 1.f / s1;
  unsigned uc = HbU[(unsigned)c * 64 + l];
  float a00 = w0 * bflo(uc), a01 = w0 * bfhi(uc);
  float a10 = w1 * bflo(uc), a11 = w1 * bfhi(uc);
  float b00 = 0.f, b01 = 0.f, b10 = 0.f, b11 = 0.f;
  int i = 0;
  for (; i + 8 <= nl; i += 8) {
    int r0 = sedge[p0 + i + 0].x, r1 = sedge[p0 + i + 1].x;
    int r2 = sedge[p0 + i + 2].x, r3 = sedge[p0 + i + 3].x;
    int r4 = sedge[p0 + i + 4].x, r5 = sedge[p0 + i + 5].x;
    int r6 = sedge[p0 + i + 6].x, r7 = sedge[p0 + i + 7].x;
    unsigned u0 = HbU[(unsigned)r0 * 64 + l];
    unsigned u1 = HbU[(unsigned)r1 * 64 + l];
    unsigned u2 = HbU[(unsigned)r2 * 64 + l];
    unsigned u3 = HbU[(unsigned)r3 * 64 + l];
    unsigned u4 = HbU[(unsigned)r4 * 64 + l];
    unsigned u5 = HbU[(unsigned)r5 * 64 + l];
    unsigned u6 = HbU[(unsigned)r6 * 64 + l];
    unsigned u7 = HbU[(unsigned)r7 * 64 + l];
    float2 f0 = lsc[slot][i + 0], f1 = lsc[slot][i + 1];
    float2 f2 = lsc[slot][i + 2], f3 = lsc[slot][i + 3];
    float2 f4 = lsc[slot][i + 4], f5 = lsc[slot][i + 5];
    float2 f6 = lsc[slot][i + 6], f7 = lsc[slot][i + 7];
    a00 += f0.x * bflo(u0); a01 += f0.x * bfhi(u0); a10 += f0.y * bflo(u0); a11 += f0.y * bfhi(u0);
    b00 += f1.x * bflo(u1); b01 += f1.x * bfhi(u1); b10 += f1.y * bflo(u1); b11 += f1.y * bfhi(u1);
    a00 += f2.x * bflo(u2); a01 += f2.x * bfhi(u2); a10 += f2.y * bflo(u2); a11 += f2.y * bfhi(u2);
    b00 += f3.x * bflo(u3); b01 += f3.x * bfhi(u3); b10 += f3.y * bflo(u3); b11 += f3.y * bfhi(u3);
    a00 += f4.x * bflo(u4); a01 += f4.x * bfhi(u4); a10 += f4.y * bflo(u4); a11 += f4.y * bfhi(u4);
    b00 += f5.x * bflo(u5); b01 += f5.x * bfhi(u5); b10 += f5.y * bflo(u5); b11 += f5.y * bfhi(u5);
    a00 += f6.x * bflo(u6); a01 += f6.x * bfhi(u6); a10 += f6.y * bflo(u6); a11 += f6.y * bfhi(u6);
    b00 += f7.x * bflo(u7); b01 += f7.x * bfhi(u7); b10 += f7.y * bflo(u7); b11 += f7.y * bfhi(u7);
  }
  for (; i < nl; i++) {
    int r0 = sedge[p0 + i].x;
    unsigned u0 = HbU[(unsigned)r0 * 64 + l];
    float2 f0 = lsc[slot][i];
    a00 += f0.x * bflo(u0); a01 += f0.x * bfhi(u0);
    a10 += f0.y * bflo(u0); a11 += f0.y * bfhi(u0);
  }
  for (int p = p0 + MAXDEG; p < p1; p++) {   // rare tail: recompute alpha
    int r = sedge[p].x;
    float2 av = ((const float2*)asrc)[r];
    float e0 = av.x + adc.x; e0 = e0 > 0.f ? e0 : 0.2f * e0;
    float e1 = av.y + adc.y; e1 = e1 > 0.f ? e1 : 0.2f * e1;
    float al0 = __expf(e0 - m0), al1 = __expf(e1 - m1);
    unsigned u0 = HbU[(unsigned)r * 64 + l];
    a00 += al0 * bflo(u0); a01 += al0 * bfhi(u0);
    a10 += al1 * bflo(u0); a11 += al1 * bfhi(u0);
  }
  AggU[(unsigned)c * 128 + l]      = pack2((a00 + b00) * inv0, (a01 + b01) * inv0);
  AggU[(unsigned)c * 128 + 64 + l] = pack2((a10 + b10) * inv1, (a11 + b11) * inv1);
}

// XT = 0.5*(Agg @ Wp) + b (+relu); bf16 LDS staging, row-split waves,
// 2 cols/lane. Also emits XTb bf16.
__global__ __launch_bounds__(128) void post_gemm_kernel(
    const unsigned* __restrict__ AggU, const float* __restrict__ Wp,
    const float* __restrict__ b, float* __restrict__ XT,
    unsigned short* __restrict__ XTb, int relu, int N) {
  __shared__ unsigned az[GROWS][128];   // 8 KB: row = 256 bf16
  int n0 = blockIdx.x * GROWS;
  int t = threadIdx.x;
  {
    const uint4* src = (const uint4*)AggU;   // row = 32 uint4
    for (int i = t; i < GROWS * 32; i += 128) {
      int r = i >> 5, cch = i & 31;
      int n = n0 + r;
      uint4 v = (n < N) ? src[(size_t)n * 32 + cch] : make_uint4(0u, 0u, 0u, 0u);
      *(uint4*)&az[r][cch * 4] = v;
    }
  }
  __syncthreads();
  int w = t >> 6;    // wave: rows w*8 .. w*8+7
  int l = t & 63;    // cols l and l+64
  float acc0[8], acc1[8];
  #pragma unroll
  for (int r = 0; r < 8; r++) { acc0[r] = 0.f; acc1[r] = 0.f; }
  for (int k8 = 0; k8 < 256; k8 += 8) {
    float wA[8], wB[8];
    #pragma unroll
    for (int q = 0; q < 8; q++) {
      wA[q] = Wp[(k8 + q) * C + l];
      wB[q] = Wp[(k8 + q) * C + l + 64];
    }
    #pragma unroll
    for (int r = 0; r < 8; r++) {
      uint4 u = *(const uint4*)&az[w * 8 + r][k8 >> 1];
      float v0 = bflo(u.x), v1 = bfhi(u.x), v2 = bflo(u.y), v3 = bfhi(u.y);
      float v4 = bflo(u.z), v5 = bfhi(u.z), v6 = bflo(u.w), v7 = bfhi(u.w);
      acc0[r] += v0*wA[0] + v1*wA[1] + v2*wA[2] + v3*wA[3]
               + v4*wA[4] + v5*wA[5] + v6*wA[6] + v7*wA[7];
      acc1[r] += v0*wB[0] + v1*wB[1] + v2*wB[2] + v3*wB[3]
               + v4*wB[4] + v5*wB[5] + v6*wB[6] + v7*wB[7];
    }
  }
  float bA = b[l], bB = b[l + 64];
  #pragma unroll
  for (int r = 0; r < 8; r++) {
    int n = n0 + w * 8 + r;
    if (n < N) {
      float vA = 0.5f * acc0[r] + bA;
      float vB = 0.5f * acc1[r] + bB;
      if (relu) { vA = fmaxf(vA, 0.f); vB = fmaxf(vB, 0.f); }
      XT[(size_t)n * C + l]      = vA;
      XT[(size_t)n * C + l + 64] = vB;
      XTb[(size_t)n * C + l]      = f2bf(vA);
      XTb[(size_t)n * C + l + 64] = f2bf(vB);
    }
  }
}

// gated blend: single K=256 GEMM over [xt|x] (bf16 LDS) vs Wz=[fc1;fc2] (f32).
// Epilogue uses exact f32 xt/x from global. Optional bf16 copy + dots.
__global__ __launch_bounds__(128) void blend_kernel(
    const unsigned* __restrict__ XTbU, const unsigned* __restrict__ XbU,
    const float* __restrict__ XTf, const float* __restrict__ Xf,
    const float* __restrict__ Wz, const float* __restrict__ fc1b,
    const float* __restrict__ fc2b, const float* __restrict__ pb,
    float* __restrict__ out, unsigned short* __restrict__ Hb2,
    const float* __restrict__ wsv, const float* __restrict__ wdv,
    float* __restrict__ asrc, float* __restrict__ adst, int dots, int N) {
  __shared__ unsigned az[GROWS][128];   // 8 KB: row = [xt 128bf16 | x 128bf16]
  __shared__ float xls[GROWS * 132];    // 8.4 KB (dots staging)
  int n0 = blockIdx.x * GROWS;
  int t = threadIdx.x;
  {
    const uint4* s1 = (const uint4*)XTbU;  // row = 16 uint4
    const uint4* s2 = (const uint4*)XbU;
    for (int i = t; i < GROWS * 32; i += 128) {
      int r = i >> 5, cch = i & 31;
      int n = n0 + r;
      uint4 v;
      if (n < N) v = (cch < 16) ? s1[(size_t)n * 16 + cch] : s2[(size_t)n * 16 + (cch - 16)];
      else v = make_uint4(0u, 0u, 0u, 0u);
      *(uint4*)&az[r][cch * 4] = v;
    }
  }
  __syncthreads();
  int w = t >> 6;    // wave: rows w*8 .. w*8+7
  int l = t & 63;    // cols l and l+64
  float acc0[8], acc1[8];
  #pragma unroll
  for (int r = 0; r < 8; r++) { acc0[r] = 0.f; acc1[r] = 0.f; }
  for (int k8 = 0; k8 < 256; k8 += 8) {
    float wA[8], wB[8];
    #pragma unroll
    for (int q = 0; q < 8; q++) {
      wA[q] = Wz[(k8 + q) * C + l];
      wB[q] = Wz[(k8 + q) * C + l + 64];
    }
    #pragma unroll
    for (int r = 0; r < 8; r++) {
      uint4 u = *(const uint4*)&az[w * 8 + r][k8 >> 1];
      float v0 = bflo(u.x), v1 = bfhi(u.x), v2 = bflo(u.y), v3 = bfhi(u.y);
      float v4 = bflo(u.z), v5 = bfhi(u.z), v6 = bflo(u.w), v7 = bfhi(u.w);
      acc0[r] += v0*wA[0] + v1*wA[1] + v2*wA[2] + v3*wA[3]
               + v4*wA[4] + v5*wA[5] + v6*wA[6] + v7*wA[7];
      acc1[r] += v0*wB[0] + v1*wB[1] + v2*wB[2] + v3*wB[3]
               + v4*wB[4] + v5*wB[5] + v6*wB[6] + v7*wB[7];
    }
  }
  float bbA = fc1b[l] + fc2b[l] + pb[l];
  float bbB = fc1b[l + 64] + fc2b[l + 64] + pb[l + 64];
  #pragma unroll
  for (int r = 0; r < 8; r++) {
    int rr = w * 8 + r;
    int n = n0 + rr;
    if (n < N) {
      float xtA = XTf[(size_t)n * C + l],      xA = Xf[(size_t)n * C + l];
      float xtB = XTf[(size_t)n * C + l + 64], xB = Xf[(size_t)n * C + l + 64];
      float tA = acc0[r] + bbA, tB = acc1[r] + bbB;
      float zA = 1.f / (1.f + __expf(-tA));
      float zB = 1.f / (1.f + __expf(-tB));
      float oA = zA * xtA + (1.f - zA) * xA;
      float oB = zB * xtB + (1.f - zB) * xB;
      out[(size_t)n * C + l]      = oA;
      out[(size_t)n * C + l + 64] = oB;
      if (dots) {
        Hb2[(size_t)n * C + l]      = f2bf(oA);
        Hb2[(size_t)n * C + l + 64] = f2bf(oB);
      }
      xls[rr * 132 + l] = oA;
      xls[rr * 132 + l + 64] = oB;
    } else {
      xls[rr * 132 + l] = 0.f;
      xls[rr * 132 + l + 64] = 0.f;
    }
  }
  if (!dots) return;
  __syncthreads();
  int r = t >> 3, sub = t & 7;
  float sa0 = 0.f, sd0 = 0.f, sa1 = 0.f, sd1 = 0.f;
  for (int k = sub; k < C; k += 8) {
    float v = xls[r * 132 + k];
    sa0 += v * wsv[k];      sd0 += v * wdv[k];
    sa1 += v * wsv[C + k];  sd1 += v * wdv[C + k];
  }
  #pragma unroll
  for (int o = 4; o > 0; o >>= 1) {
    sa0 += __shfl_down(sa0, o); sd0 += __shfl_down(sd0, o);
    sa1 += __shfl_down(sa1, o); sd1 += __shfl_down(sd1, o);
  }
  int n = n0 + r;
  if (sub == 0 && n < N) {
    asrc[n * 2 + 0] = sa0; adst[n * 2 + 0] = sd0;
    asrc[n * 2 + 1] = sa1; adst[n * 2 + 1] = sd1;
  }
}

// ---- launch ----------------------------------------------------------------

extern "C" void kernel_launch(void* const* d_in, const int* in_sizes, int n_in,
                              void* d_out, int out_size, void* d_ws, size_t ws_size,
                              hipStream_t stream) {
  const float* x_in  = (const float*)d_in[0];
  const int*   ei    = (const int*)d_in[1];
  const float* ew    = (const float*)d_in[2];
  const float* gcn_W = (const float*)d_in[3];
  const float* gcn_b = (const float*)d_in[4];
  const float* g1_W  = (const float*)d_in[5];
  const float* g1_as = (const float*)d_in[6];
  const float* g1_ad = (const float*)d_in[7];
  const float* g1_b  = (const float*)d_in[8];
  const float* g2_W  = (const float*)d_in[9];
  const float* g2_as = (const float*)d_in[10];
  const float* g2_ad = (const float*)d_in[11];
  const float* g2_b  = (const float*)d_in[12];
  const float* fc1_W = (const float*)d_in[13];
  const float* fc1_b = (const float*)d_in[14];
  const float* fc2_W = (const float*)d_in[15];
  const float* fc2_b = (const float*)d_in[16];
  const float* pb    = (const float*)d_in[17];

  const int N = in_sizes[0] / F_IN;
  const int E = in_sizes[2];
  const int* row = ei;
  const int* col = ei + E;

  char* ws = (char*)d_ws;
  size_t o = 0;
  auto alloc = [&](size_t bytes) -> void* {
    void* p = ws + o;
    o += (bytes + 255) & ~(size_t)255;
    return p;
  };
  int*   cnt   = (int*)alloc((size_t)(N + 1) * 4);
  int*   cur   = (int*)alloc((size_t)N * 4);
  float* deg   = (float*)alloc((size_t)N * 4);
  size_t zero_bytes = o;                     // cnt+cur+deg at ws start
  int*   off   = (int*)alloc((size_t)(N + 1) * 4);
  float* dinv  = (float*)alloc((size_t)N * 4);
  int*   bsum  = (int*)alloc(256 * 4);
  int2*  sedge = (int2*)alloc((size_t)E * 8);
  float* attv  = (float*)alloc(1024 * 4);                 // ws1,wd1,ws2,wd2
  float* Wp1   = (float*)alloc((size_t)256 * C * 4);
  float* Wp2   = (float*)alloc((size_t)256 * C * 4);
  float* Wz    = (float*)alloc((size_t)256 * C * 4);
  float* asrc  = (float*)alloc((size_t)N * 2 * 4);
  float* adst  = (float*)alloc((size_t)N * 2 * 4);
  unsigned* X36U = (unsigned*)alloc((size_t)N * (FP / 2) * 4);   // bf16 [N,36]
  float* Xagg  = (float*)alloc((size_t)N * FP * 4);
  float* H     = (float*)alloc((size_t)N * C * 4);        // gcn out
  unsigned short* Hb  = (unsigned short*)alloc((size_t)N * C * 2);
  unsigned* AggU = (unsigned*)alloc((size_t)N * 128 * 4); // bf16 [N,2,128]
  float* XT    = (float*)alloc((size_t)N * C * 4);        // gat out
  unsigned short* XTb = (unsigned short*)alloc((size_t)N * C * 2);
  float* H2    = (float*)alloc((size_t)N * C * 4);        // blend1 out
  unsigned short* Hb2 = (unsigned short*)alloc((size_t)N * C * 2);
  (void)ws_size; (void)n_in; (void)out_size;

  float* ws1 = attv + 0,   *wd1 = attv + 256;
  float* ws2 = attv + 512, *wd2 = attv + 768;

  hipMemsetAsync(d_ws, 0, zero_bytes, stream);

  const int tb = 256;
  const int nP = N + 1;
  const int nb = (nP + 1023) / 1024;

  // parameter prep (input-only deps)
  prep_dots_kernel<<<4, 256, 0, stream>>>(g1_W, g1_as, g1_ad, g2_W, g2_as, g2_ad, attv);
  prep_repack_kernel<<<256, 256, 0, stream>>>(g1_W, g2_W, Wp1, Wp2);
  prep_wz_kernel<<<128, 256, 0, stream>>>(fc1_W, fc2_W, Wz);
  convert_x_kernel<<<(N * (FP / 2) + tb - 1) / tb, tb, 0, stream>>>(x_in, X36U, N);

  // CSR build
  count_kernel<<<(E + tb - 1) / tb, tb, 0, stream>>>(col, ew, cnt, deg, E);
  scan1_kernel<<<nb, 256, 0, stream>>>(cnt, off, bsum, nP);
  scan2_kernel<<<1, 256, 0, stream>>>(bsum, nb);
  scan3_dinv_kernel<<<(nP + tb - 1) / tb, tb, 0, stream>>>(off, bsum, deg, dinv, nP, N);
  scatter_kernel<<<(E + tb - 1) / tb, tb, 0, stream>>>(row, col, ew, off, dinv, cur, sedge, E);

  // GCN: aggregate 33-dim inputs, then project (+relu, +layer1 score dots)
  gcn_agg33_kernel<<<(N + 3) / 4, 256, 0, stream>>>(X36U, off, sedge, dinv, Xagg, N);
  gemm36_kernel<<<(N + GROWS - 1) / GROWS, C, 0, stream>>>(Xagg, gcn_W, gcn_b, ws1, wd1,
                                                           H, Hb, asrc, adst, N);

  // GAT layer 1: softmax+aggregate (input space), project, blend (+layer2 dots)
  gat_agg_kernel<<<(N + 3) / 4, 256, 0, stream>>>((const unsigned*)Hb, asrc, adst, off, sedge, AggU, N);
  post_gemm_kernel<<<(N + GROWS - 1) / GROWS, C, 0, stream>>>(AggU, Wp1, g1_b, XT, XTb, 1, N);
  blend_kernel<<<(N + GROWS - 1) / GROWS, C, 0, stream>>>(
      (const unsigned*)XTb, (const unsigned*)Hb, XT, H, Wz, fc1_b, fc2_b, pb,
      H2, Hb2, ws2, wd2, asrc, adst, 1, N);

  // GAT layer 2 + final blend into d_out
  gat_agg_kernel<<<(N + 3) / 4, 256, 0, stream>>>((const unsigned*)Hb2, asrc, adst, off, sedge, AggU, N);
  post_gemm_kernel<<<(N + GROWS - 1) / GROWS, C, 0, stream>>>(AggU, Wp2, g2_b, XT, XTb, 0, N);
  blend_kernel<<<(N + GROWS - 1) / GROWS, C, 0, stream>>>(
      (const unsigned*)XTb, (const unsigned*)Hb2, XT, H2, Wz, fc1_b, fc2_b, pb,
      (float*)d_out, (unsigned short*)0, ws2, wd2, asrc, adst, 0, N);
}